// Round 4
// baseline (142.575 us; speedup 1.0000x reference)
//
#include <hip/hip_runtime.h>
#include <math.h>

#define FF 2048

typedef __attribute__((ext_vector_type(8))) short short8;
typedef __attribute__((ext_vector_type(4))) float floatx4;

// ws float offsets. Split-K: S/H=32, sel=16, mem=16, logits=32.
#define OFF_SPART 0                      // [32][64][1000]
#define OFF_HPART 2048000                // [32][64][1000]
#define OFF_SELP  4096000                // [16][64][2048]
#define OFF_MEMP  6193152                // [16][64][2048]
#define OFF_LOGP  8290304                // [32][64][1000]
#define OFF_V     10338304               // [64][1024] softmax result (padded)
#define OFF_FEAT  10403840               // [64][2048]
#define OFF_CN2   10534912               // [1000]
#define OFF_WINV  10535912               // [1000]
#define OFF_XN2   10536912               // [64]
#define OFF_REACH 10536976               // [64]
#define OFF_NRM2P 10537040               // [64][8]

#define TP 40   // LDS tile pitch in shorts: 32 data + 8 pad

__device__ __forceinline__ void split2(float f, ushort& h, ushort& l) {
  unsigned u = __float_as_uint(f);
  float r = f - __uint_as_float(u & 0xffff0000u);
  h = (ushort)(u >> 16);
  l = (ushort)(__float_as_uint(r) >> 16);
}

struct R2 { float4 a, b; };

// Row-major-K matrix, 64 rows x 32 k per tile.
__device__ __forceinline__ void load_bt(const float* __restrict__ M, int ldK, int rowBase,
                                        int nrows, int k0, R2& s, int t) {
  int r = t >> 2, q = t & 3;
  int grow = rowBase + r;
  const float* src = M + (size_t)grow * ldK + k0 + q * 8;
  s.a = make_float4(0.f, 0.f, 0.f, 0.f);
  s.b = s.a;
  if (grow < nrows) {
    s.a = *(const float4*)src;
    s.b = *(const float4*)(src + 4);
  }
}

__device__ __forceinline__ void store_bt(const R2& s, ushort* __restrict__ hi,
                                         ushort* __restrict__ lo, int t) {
  int r = t >> 2, q = t & 3;
#pragma unroll
  for (int h = 0; h < 2; ++h) {
    const float4& v = h ? s.b : s.a;
    ushort4 hv, lv;
    split2(v.x, hv.x, lv.x); split2(v.y, hv.y, lv.y);
    split2(v.z, hv.z, lv.z); split2(v.w, hv.w, lv.w);
    int base = r * TP + q * 8 + h * 4;
    *(ushort4*)(hi + base) = hv;
    *(ushort4*)(lo + base) = lv;
  }
}

// Row-major-N matrix B[k][n]: 32 k-rows x 64 n-cols, stored transposed [n][k].
__device__ __forceinline__ void load_tr(const float* __restrict__ M, int ldN, int k0, int kmax,
                                        int n0, R2& s, int t) {
  int kk = t >> 3, c8 = (t & 7) * 8;
  int gk = k0 + kk;
  const float* src = M + (size_t)gk * ldN + n0 + c8;
  s.a = make_float4(0.f, 0.f, 0.f, 0.f);
  s.b = s.a;
  if (gk < kmax) {
    s.a = *(const float4*)src;
    s.b = *(const float4*)(src + 4);
  }
}

__device__ __forceinline__ void store_tr(const R2& s, ushort* __restrict__ hi,
                                         ushort* __restrict__ lo, int t) {
  int kk = t >> 3, c8 = (t & 7) * 8;
#pragma unroll
  for (int j = 0; j < 8; ++j) {
    float f = (j < 4) ? ((const float*)&s.a)[j] : ((const float*)&s.b)[j - 4];
    ushort h, l;
    split2(f, h, l);
    hi[(c8 + j) * TP + kk] = h;
    lo[(c8 + j) * TP + kk] = l;
  }
}

#define MFMA(a, b, c) __builtin_amdgcn_mfma_f32_16x16x32_bf16(a, b, c, 0, 0, 0)

__device__ __forceinline__ void mfma_tile(const ushort* __restrict__ Ah, const ushort* __restrict__ Al,
                                          const ushort* __restrict__ Bh, const ushort* __restrict__ Bl,
                                          int ln15, int q8, int mh, int nh, floatx4 (&acc)[2][2]) {
  short8 ah[2], al[2];
#pragma unroll
  for (int i = 0; i < 2; ++i) {
    int row = (mh * 2 + i) * 16 + ln15;
    ah[i] = *(const short8*)(Ah + row * TP + q8);
    al[i] = *(const short8*)(Al + row * TP + q8);
  }
#pragma unroll
  for (int j = 0; j < 2; ++j) {
    int brow = (nh * 2 + j) * 16 + ln15;
    short8 bh = *(const short8*)(Bh + brow * TP + q8);
    short8 bl = *(const short8*)(Bl + brow * TP + q8);
#pragma unroll
    for (int i = 0; i < 2; ++i) {
      acc[i][j] = MFMA(ah[i], bh, acc[i][j]);
      acc[i][j] = MFMA(ah[i], bl, acc[i][j]);
      acc[i][j] = MFMA(al[i], bh, acc[i][j]);
    }
  }
}

// ====== Kernel 1: norms + S/H (16 tiles x 32 splits x 2) + sel (32 tiles x 16) ======
// 1536 blocks: [0,1024) S/H with K=64 (2 k-steps preloaded), [1024,1536) sel K=128.
__global__ __launch_bounds__(256) void k1_gemm1(
    const float* __restrict__ x, const float* __restrict__ cent,
    const float* __restrict__ whall, const float* __restrict__ wsel,
    const float* __restrict__ wcos, float* __restrict__ ws) {
  __shared__ __align__(16) ushort u_lds[4 * 64 * TP];
  ushort* Ah = u_lds;
  ushort* Al = u_lds + 64 * TP;
  ushort* Bh = u_lds + 2 * 64 * TP;
  ushort* Bl = u_lds + 3 * 64 * TP;
  int bx = blockIdx.x, t = threadIdx.x;
  int lane = t & 63, w = t >> 6;
  int ln15 = t & 15, lq = (t >> 4) & 3, q8 = lq * 8;
  int mh = w & 1, nh = w >> 1;

  // ---- norms: |cent_r|^2, 1/|wcos_r|, |x_b|^2 (blocks 0..515) ----
  int r = bx * 4 + w;
  if (r < 2064) {
    const float* src = (r < 1000) ? cent + (size_t)r * FF
                     : (r < 2000) ? wcos + (size_t)(r - 1000) * FF
                                  : x + (size_t)(r - 2000) * FF;
    float s = 0.f;
#pragma unroll
    for (int i = 0; i < 8; ++i) {
      float4 v = *(const float4*)(src + i * 256 + lane * 4);
      s += v.x * v.x + v.y * v.y + v.z * v.z + v.w * v.w;
    }
#pragma unroll
    for (int off = 32; off > 0; off >>= 1) s += __shfl_down(s, off, 64);
    if (lane == 0) {
      if (r < 1000) ws[OFF_CN2 + r] = s;
      else if (r < 2000) ws[OFF_WINV + (r - 1000)] = 1.f / sqrtf(s);
      else ws[OFF_XN2 + (r - 2000)] = s;
    }
  }

  floatx4 acc[2][2];
#pragma unroll
  for (int i = 0; i < 2; ++i)
#pragma unroll
    for (int j = 0; j < 2; ++j) acc[i][j] = (floatx4){0.f, 0.f, 0.f, 0.f};

  if (bx < 1024) {
    // S (mat=0) / H (mat=1): K=64 per block, both 32-k chunks preloaded.
    int mat = bx >> 9;
    int b2 = bx & 511;
    int tile = b2 & 15, ks = b2 >> 4;     // ks in [0,32)
    int n0 = tile * 64;
    const float* Bm = mat ? whall : cent;
    R2 rA[2], rB[2];
    load_bt(x,  FF, 0,  64,   ks * 64,      rA[0], t);
    load_bt(Bm, FF, n0, 1000, ks * 64,      rB[0], t);
    load_bt(x,  FF, 0,  64,   ks * 64 + 32, rA[1], t);
    load_bt(Bm, FF, n0, 1000, ks * 64 + 32, rB[1], t);
#pragma unroll
    for (int kc = 0; kc < 2; ++kc) {
      __syncthreads();
      store_bt(rA[kc], Ah, Al, t);
      store_bt(rB[kc], Bh, Bl, t);
      __syncthreads();
      mfma_tile(Ah, Al, Bh, Bl, ln15, q8, mh, nh, acc);
    }
    float* outp = ws + (mat ? OFF_HPART : OFF_SPART) + (size_t)ks * 64000;
#pragma unroll
    for (int i = 0; i < 2; ++i)
#pragma unroll
      for (int j = 0; j < 2; ++j) {
        int gn = n0 + (nh * 2 + j) * 16 + ln15;
        if (gn < 1000) {
#pragma unroll
          for (int rr = 0; rr < 4; ++rr) {
            int gm = (mh * 2 + i) * 16 + lq * 4 + rr;
            outp[gm * 1000 + gn] = acc[i][j][rr];
          }
        }
      }
  } else {
    // sel = x @ wsel^T : K=128 per block (4 k-steps, depth-2 prefetch).
    int b2 = bx - 1024;
    int tile = b2 & 31, ks = b2 >> 5;     // ks in [0,16)
    int n0 = tile * 64;
    R2 rA[2], rB[2];
    load_bt(x,    FF, 0,  64,   ks * 128,      rA[0], t);
    load_bt(wsel, FF, n0, 2048, ks * 128,      rB[0], t);
    load_bt(x,    FF, 0,  64,   ks * 128 + 32, rA[1], t);
    load_bt(wsel, FF, n0, 2048, ks * 128 + 32, rB[1], t);
#pragma unroll
    for (int kc = 0; kc < 4; ++kc) {
      __syncthreads();
      store_bt(rA[kc & 1], Ah, Al, t);
      store_bt(rB[kc & 1], Bh, Bl, t);
      if (kc + 2 < 4) {
        load_bt(x,    FF, 0,  64,   ks * 128 + (kc + 2) * 32, rA[kc & 1], t);
        load_bt(wsel, FF, n0, 2048, ks * 128 + (kc + 2) * 32, rB[kc & 1], t);
      }
      __syncthreads();
      mfma_tile(Ah, Al, Bh, Bl, ln15, q8, mh, nh, acc);
    }
    float* selp = ws + OFF_SELP + (size_t)ks * 131072;
#pragma unroll
    for (int i = 0; i < 2; ++i)
#pragma unroll
      for (int j = 0; j < 2; ++j) {
        int gn = n0 + (nh * 2 + j) * 16 + ln15;
#pragma unroll
        for (int rr = 0; rr < 4; ++rr) {
          int gm = (mh * 2 + i) * 16 + lq * 4 + rr;
          selp[gm * 2048 + gn] = acc[i][j][rr];
        }
      }
  }
}

// ====== Kernel 2: reduce partials, min-dist + softmax -> V, reach (64 x 1024) ======
__global__ __launch_bounds__(1024) void k2_softmax(const float* __restrict__ bhall,
                                                   float* __restrict__ ws) {
  __shared__ float red[1024];
  int b = blockIdx.x, t = threadIdx.x;
  float xn = ws[OFF_XN2 + b];
  float lmin = 3.0e38f, lmax = -3.0e38f;
  float Hf = 0.f;
  if (t < 1000) {
    float S = 0.f, H = 0.f;
#pragma unroll
    for (int ks = 0; ks < 32; ++ks) {
      S += ws[OFF_SPART + (size_t)ks * 64000 + b * 1000 + t];
      H += ws[OFF_HPART + (size_t)ks * 64000 + b * 1000 + t];
    }
    Hf = H + bhall[t];
    float d2 = xn - 2.f * S + ws[OFF_CN2 + t];
    lmin = d2;
    lmax = Hf;
  }
  red[t] = lmin; __syncthreads();
  for (int s = 512; s > 0; s >>= 1) { if (t < s) red[t] = fminf(red[t], red[t + s]); __syncthreads(); }
  float bmin = red[0]; __syncthreads();
  red[t] = lmax; __syncthreads();
  for (int s = 512; s > 0; s >>= 1) { if (t < s) red[t] = fmaxf(red[t], red[t + s]); __syncthreads(); }
  float bmax = red[0]; __syncthreads();
  float e = (t < 1000) ? expf(Hf - bmax) : 0.f;
  red[t] = e; __syncthreads();
  for (int s = 512; s > 0; s >>= 1) { if (t < s) red[t] += red[t + s]; __syncthreads(); }
  float inv = 1.f / red[0];
  ws[OFF_V + b * 1024 + t] = e * inv;   // t>=1000 writes 0: pad for blind loads
  if (t == 0) ws[OFF_REACH + b] = 10.f / sqrtf(bmin);
}

// ====== Kernel 3: mem = V@cent (K=1000, 32 tiles x 16 splits, K=64 preloaded) ======
__global__ __launch_bounds__(256) void k3_mem(const float* __restrict__ cent,
                                              float* __restrict__ ws) {
  __shared__ __align__(16) ushort u_lds[4 * 64 * TP];
  ushort* Ah = u_lds;
  ushort* Al = u_lds + 64 * TP;
  ushort* Bh = u_lds + 2 * 64 * TP;
  ushort* Bl = u_lds + 3 * 64 * TP;
  int bx = blockIdx.x, t = threadIdx.x;
  int ln15 = t & 15, lq = (t >> 4) & 3, q8 = lq * 8;
  int w = t >> 6, mh = w & 1, nh = w >> 1;
  int tile = bx & 31, ks = bx >> 5;       // ks in [0,16)
  int n0 = tile * 64;
  const float* V = ws + OFF_V;

  floatx4 acc[2][2];
#pragma unroll
  for (int i = 0; i < 2; ++i)
#pragma unroll
    for (int j = 0; j < 2; ++j) acc[i][j] = (floatx4){0.f, 0.f, 0.f, 0.f};

  R2 rA[2], rB[2];
  load_bt(V, 1024, 0, 64, ks * 64,      rA[0], t);
  load_tr(cent, FF, ks * 64,      1000, n0, rB[0], t);
  load_bt(V, 1024, 0, 64, ks * 64 + 32, rA[1], t);
  load_tr(cent, FF, ks * 64 + 32, 1000, n0, rB[1], t);
#pragma unroll
  for (int kc = 0; kc < 2; ++kc) {
    __syncthreads();
    store_bt(rA[kc], Ah, Al, t);
    store_tr(rB[kc], Bh, Bl, t);
    __syncthreads();
    mfma_tile(Ah, Al, Bh, Bl, ln15, q8, mh, nh, acc);
  }
  float* memp = ws + OFF_MEMP + (size_t)ks * 131072;
#pragma unroll
  for (int i = 0; i < 2; ++i)
#pragma unroll
    for (int j = 0; j < 2; ++j) {
      int gn = n0 + (nh * 2 + j) * 16 + ln15;
#pragma unroll
      for (int rr = 0; rr < 4; ++rr) {
        int gm = (mh * 2 + i) * 16 + lq * 4 + rr;
        memp[gm * 2048 + gn] = acc[i][j][rr];
      }
    }
}

// ====== Kernel 4: fuse. 64 rows x 8 chunks, one wave each ======
__global__ __launch_bounds__(64) void k4_fuse(const float* __restrict__ x,
                                              const float* __restrict__ bsel,
                                              float* __restrict__ ws, float* __restrict__ out) {
  int bx = blockIdx.x, t = threadIdx.x;
  int row = bx >> 3, ch = bx & 7;
  int f = ch * 256 + t * 4;
  const float* selp = ws + OFF_SELP + (size_t)row * 2048 + f;
  const float* memp = ws + OFF_MEMP + (size_t)row * 2048 + f;
  floatx4 sp = {0.f, 0.f, 0.f, 0.f}, mm = {0.f, 0.f, 0.f, 0.f};
#pragma unroll
  for (int ks = 0; ks < 16; ++ks) {
    sp += *(const floatx4*)(selp + (size_t)ks * 131072);
    mm += *(const floatx4*)(memp + (size_t)ks * 131072);
  }
  float4 bs4 = *(const float4*)(bsel + f);
  float4 x4  = *(const float4*)(x + (size_t)row * 2048 + f);
  float rch = ws[OFF_REACH + row];
  float4 inf4;
  floatx4 ft4;
  float nrm2 = 0.f;
#pragma unroll
  for (int j = 0; j < 4; ++j) {
    float sel = tanhf(sp[j] + ((float*)&bs4)[j]);
    float inf = sel * mm[j];
    float ft = rch * (((float*)&x4)[j] + inf);
    ((float*)&inf4)[j] = inf;
    ft4[j] = ft;
    nrm2 += ft * ft;
  }
  *(float4*)(out + 64000 + (size_t)row * 2048 + f) = x4;     // direct_feature
  *(float4*)(out + 195072 + (size_t)row * 2048 + f) = inf4;  // infused_feature
  *(floatx4*)(ws + OFF_FEAT + (size_t)row * 2048 + f) = ft4;
#pragma unroll
  for (int off = 32; off > 0; off >>= 1) nrm2 += __shfl_down(nrm2, off, 64);
  if (t == 0) ws[OFF_NRM2P + row * 8 + ch] = nrm2;
}

// ====== Kernel 5: logp = feat@wcos^T (16 tiles x 32 splits, K=64 preloaded) ======
__global__ __launch_bounds__(256) void k5_logits(const float* __restrict__ wcos,
                                                 float* __restrict__ ws) {
  __shared__ __align__(16) ushort u_lds[4 * 64 * TP];
  ushort* Ah = u_lds;
  ushort* Al = u_lds + 64 * TP;
  ushort* Bh = u_lds + 2 * 64 * TP;
  ushort* Bl = u_lds + 3 * 64 * TP;
  int bx = blockIdx.x, t = threadIdx.x;
  int tile = bx & 15, ks = bx >> 4;   // ks in [0,32)
  int n0 = tile * 64;
  int ln15 = t & 15, lq = (t >> 4) & 3, q8 = lq * 8;
  int w = t >> 6, mh = w & 1, nh = w >> 1;
  const float* feat = ws + OFF_FEAT;

  floatx4 acc[2][2];
#pragma unroll
  for (int i = 0; i < 2; ++i)
#pragma unroll
    for (int j = 0; j < 2; ++j) acc[i][j] = (floatx4){0.f, 0.f, 0.f, 0.f};

  R2 rA[2], rB[2];
  load_bt(feat, FF, 0,  64,   ks * 64,      rA[0], t);
  load_bt(wcos, FF, n0, 1000, ks * 64,      rB[0], t);
  load_bt(feat, FF, 0,  64,   ks * 64 + 32, rA[1], t);
  load_bt(wcos, FF, n0, 1000, ks * 64 + 32, rB[1], t);
#pragma unroll
  for (int kc = 0; kc < 2; ++kc) {
    __syncthreads();
    store_bt(rA[kc], Ah, Al, t);
    store_bt(rB[kc], Bh, Bl, t);
    __syncthreads();
    mfma_tile(Ah, Al, Bh, Bl, ln15, q8, mh, nh, acc);
  }
  float* logp = ws + OFF_LOGP + (size_t)ks * 64000;
#pragma unroll
  for (int i = 0; i < 2; ++i)
#pragma unroll
    for (int j = 0; j < 2; ++j) {
      int gn = n0 + (nh * 2 + j) * 16 + ln15;
      if (gn < 1000) {
#pragma unroll
        for (int rr = 0; rr < 4; ++rr) {
          int gm = (mh * 2 + i) * 16 + lq * 4 + rr;
          logp[gm * 1000 + gn] = acc[i][j][rr];
        }
      }
    }
}

// ====== Kernel 6: reduce 32 logit partials, apply cos-norm scales (500 x 128) ======
__global__ __launch_bounds__(128) void k6_final(float* __restrict__ ws, float* __restrict__ out) {
  int idx = blockIdx.x * 128 + threadIdx.x;   // < 64000
  const float* logp = ws + OFF_LOGP + idx;
  float s = 0.f;
#pragma unroll
  for (int ks = 0; ks < 32; ++ks)
    s += logp[(size_t)ks * 64000];
  int bb = idx / 1000;
  int cc = idx - bb * 1000;
  float n2 = 0.f;
#pragma unroll
  for (int q = 0; q < 8; ++q) n2 += ws[OFF_NRM2P + bb * 8 + q];
  float sfac = 16.f / (1.f + sqrtf(n2));
  out[idx] = s * sfac * ws[OFF_WINV + cc];
}

extern "C" void kernel_launch(void* const* d_in, const int* in_sizes, int n_in,
                              void* d_out, int out_size, void* d_ws, size_t ws_size,
                              hipStream_t stream) {
  const float* x     = (const float*)d_in[0];
  const float* cent  = (const float*)d_in[1];
  const float* whall = (const float*)d_in[2];
  const float* bhall = (const float*)d_in[3];
  const float* wsel  = (const float*)d_in[4];
  const float* bsel  = (const float*)d_in[5];
  const float* wcos  = (const float*)d_in[6];
  float* out = (float*)d_out;
  float* ws  = (float*)d_ws;

  hipLaunchKernelGGL(k1_gemm1,   dim3(1536), dim3(256),  0, stream, x, cent, whall, wsel, wcos, ws);
  hipLaunchKernelGGL(k2_softmax, dim3(64),   dim3(1024), 0, stream, bhall, ws);
  hipLaunchKernelGGL(k3_mem,     dim3(512),  dim3(256),  0, stream, cent, ws);
  hipLaunchKernelGGL(k4_fuse,    dim3(512),  dim3(64),   0, stream, x, bsel, ws, out);
  hipLaunchKernelGGL(k5_logits,  dim3(512),  dim3(256),  0, stream, wcos, ws);
  hipLaunchKernelGGL(k6_final,   dim3(500),  dim3(128),  0, stream, ws, out);
}

// Round 5
// 120.073 us; speedup vs baseline: 1.1874x; 1.1874x over previous
//
#include <hip/hip_runtime.h>
#include <math.h>

#define FF 2048

typedef __attribute__((ext_vector_type(8))) short short8;
typedef __attribute__((ext_vector_type(4))) float floatx4;

// ws float offsets. Split-K: S/H=16, sel=16, mem=8, logits=16.
#define OFF_SPART 0                      // [16][64][1000]
#define OFF_HPART 1024000                // [16][64][1000]
#define OFF_SELP  2048000                // [16][64][2048]
#define OFF_MEMP  4145152                // [8][64][2048]
#define OFF_LOGP  5193728                // [16][64][1000]
#define OFF_V     7241728                // [64][1024] softmax result (padded)
#define OFF_FEAT  7307264                // [64][2048]
#define OFF_CN2   7438336                // [1000]
#define OFF_WINV  7439336                // [1000]
#define OFF_XN2   7440336                // [64]
#define OFF_REACH 7440400                // [64]
#define OFF_NRM2P 7440464                // [64][8]

#define TP 40   // LDS tile pitch in shorts: 32 data + 8 pad

__device__ __forceinline__ void split2(float f, ushort& h, ushort& l) {
  unsigned u = __float_as_uint(f);
  float r = f - __uint_as_float(u & 0xffff0000u);
  h = (ushort)(u >> 16);
  l = (ushort)(__float_as_uint(r) >> 16);
}

struct R2 { float4 a, b; };

// ---- load/store split for software pipelining (depth-2 reg prefetch) ----
__device__ __forceinline__ void load_bt(const float* __restrict__ M, int ldK, int rowBase,
                                        int nrows, int k0, R2& s, int t) {
  int r = t >> 2, q = t & 3;
  int grow = rowBase + r;
  const float* src = M + (size_t)grow * ldK + k0 + q * 8;
  s.a = make_float4(0.f, 0.f, 0.f, 0.f);
  s.b = s.a;
  if (grow < nrows) {
    s.a = *(const float4*)src;
    s.b = *(const float4*)(src + 4);
  }
}

__device__ __forceinline__ void store_bt(const R2& s, ushort* __restrict__ hi,
                                         ushort* __restrict__ lo, int t) {
  int r = t >> 2, q = t & 3;
#pragma unroll
  for (int h = 0; h < 2; ++h) {
    const float4& v = h ? s.b : s.a;
    ushort4 hv, lv;
    split2(v.x, hv.x, lv.x); split2(v.y, hv.y, lv.y);
    split2(v.z, hv.z, lv.z); split2(v.w, hv.w, lv.w);
    int base = r * TP + q * 8 + h * 4;
    *(ushort4*)(hi + base) = hv;
    *(ushort4*)(lo + base) = lv;
  }
}

// Row-major-N matrix B[k][n]: 32 k-rows x 64 n-cols, stored transposed [n][k].
__device__ __forceinline__ void load_tr(const float* __restrict__ M, int ldN, int k0, int kmax,
                                        int n0, R2& s, int t) {
  int kk = t >> 3, c8 = (t & 7) * 8;
  int gk = k0 + kk;
  const float* src = M + (size_t)gk * ldN + n0 + c8;
  s.a = make_float4(0.f, 0.f, 0.f, 0.f);
  s.b = s.a;
  if (gk < kmax) {
    s.a = *(const float4*)src;
    s.b = *(const float4*)(src + 4);
  }
}

__device__ __forceinline__ void store_tr(const R2& s, ushort* __restrict__ hi,
                                         ushort* __restrict__ lo, int t) {
  int kk = t >> 3, c8 = (t & 7) * 8;
#pragma unroll
  for (int j = 0; j < 8; ++j) {
    float f = (j < 4) ? ((const float*)&s.a)[j] : ((const float*)&s.b)[j - 4];
    ushort h, l;
    split2(f, h, l);
    hi[(c8 + j) * TP + kk] = h;
    lo[(c8 + j) * TP + kk] = l;
  }
}

#define MFMA(a, b, c) __builtin_amdgcn_mfma_f32_16x16x32_bf16(a, b, c, 0, 0, 0)

__device__ __forceinline__ void mfma_tile(const ushort* __restrict__ Ah, const ushort* __restrict__ Al,
                                          const ushort* __restrict__ Bh, const ushort* __restrict__ Bl,
                                          int ln15, int q8, int mh, int nh, floatx4 (&acc)[2][2]) {
  short8 ah[2], al[2];
#pragma unroll
  for (int i = 0; i < 2; ++i) {
    int row = (mh * 2 + i) * 16 + ln15;
    ah[i] = *(const short8*)(Ah + row * TP + q8);
    al[i] = *(const short8*)(Al + row * TP + q8);
  }
#pragma unroll
  for (int j = 0; j < 2; ++j) {
    int brow = (nh * 2 + j) * 16 + ln15;
    short8 bh = *(const short8*)(Bh + brow * TP + q8);
    short8 bl = *(const short8*)(Bl + brow * TP + q8);
#pragma unroll
    for (int i = 0; i < 2; ++i) {
      acc[i][j] = MFMA(ah[i], bh, acc[i][j]);
      acc[i][j] = MFMA(ah[i], bl, acc[i][j]);
      acc[i][j] = MFMA(al[i], bh, acc[i][j]);
    }
  }
}

// ================= Kernel 1: row norms + S/H GEMMs (16 tiles x 16 splits each) =======
// 512 blocks: bx>>8==0 -> S = x@cent^T, ==1 -> H = x@whall^T. K split 16 x 128.
__global__ __launch_bounds__(256) void k1_gemm1(
    const float* __restrict__ x, const float* __restrict__ cent,
    const float* __restrict__ whall, const float* __restrict__ wcos,
    float* __restrict__ ws) {
  __shared__ __align__(16) ushort u_lds[4 * 64 * TP];
  ushort* Ah = u_lds;
  ushort* Al = u_lds + 64 * TP;
  ushort* Bh = u_lds + 2 * 64 * TP;
  ushort* Bl = u_lds + 3 * 64 * TP;
  int bx = blockIdx.x, t = threadIdx.x;
  int lane = t & 63, w = t >> 6;
  int ln15 = t & 15, lq = (t >> 4) & 3, q8 = lq * 8;
  int mh = w & 1, nh = w >> 1;

  // ---- norms: |cent_r|^2, 1/|wcos_r|, |x_b|^2 ----
  for (int r = bx * 4 + w; r < 2064; r += 2048) {
    const float* src = (r < 1000) ? cent + (size_t)r * FF
                     : (r < 2000) ? wcos + (size_t)(r - 1000) * FF
                                  : x + (size_t)(r - 2000) * FF;
    float s = 0.f;
#pragma unroll
    for (int i = 0; i < 8; ++i) {
      float4 v = *(const float4*)(src + i * 256 + lane * 4);
      s += v.x * v.x + v.y * v.y + v.z * v.z + v.w * v.w;
    }
#pragma unroll
    for (int off = 32; off > 0; off >>= 1) s += __shfl_down(s, off, 64);
    if (lane == 0) {
      if (r < 1000) ws[OFF_CN2 + r] = s;
      else if (r < 2000) ws[OFF_WINV + (r - 1000)] = 1.f / sqrtf(s);
      else ws[OFF_XN2 + (r - 2000)] = s;
    }
  }

  // ---- GEMM ----
  int mat = bx >> 8;               // 0=S, 1=H
  int ks = (bx >> 4) & 15;
  int tile = bx & 15;
  int n0 = tile * 64;
  const float* Bm = mat ? whall : cent;
  float* outp = ws + (mat ? OFF_HPART : OFF_SPART) + (size_t)ks * 64000;

  floatx4 acc[2][2];
#pragma unroll
  for (int i = 0; i < 2; ++i)
#pragma unroll
    for (int j = 0; j < 2; ++j) acc[i][j] = (floatx4){0.f, 0.f, 0.f, 0.f};

  R2 rA[2], rB[2];
  load_bt(x,  FF, 0,  64,   ks * 128,      rA[0], t);
  load_bt(Bm, FF, n0, 1000, ks * 128,      rB[0], t);
  load_bt(x,  FF, 0,  64,   ks * 128 + 32, rA[1], t);
  load_bt(Bm, FF, n0, 1000, ks * 128 + 32, rB[1], t);
#pragma unroll
  for (int kc = 0; kc < 4; ++kc) {
    __syncthreads();
    store_bt(rA[kc & 1], Ah, Al, t);
    store_bt(rB[kc & 1], Bh, Bl, t);
    if (kc + 2 < 4) {
      load_bt(x,  FF, 0,  64,   ks * 128 + (kc + 2) * 32, rA[kc & 1], t);
      load_bt(Bm, FF, n0, 1000, ks * 128 + (kc + 2) * 32, rB[kc & 1], t);
    }
    __syncthreads();
    mfma_tile(Ah, Al, Bh, Bl, ln15, q8, mh, nh, acc);
  }
#pragma unroll
  for (int i = 0; i < 2; ++i)
#pragma unroll
    for (int j = 0; j < 2; ++j) {
      int gn = n0 + (nh * 2 + j) * 16 + ln15;
      if (gn < 1000) {
#pragma unroll
        for (int r = 0; r < 4; ++r) {
          int gm = (mh * 2 + i) * 16 + lq * 4 + r;
          outp[gm * 1000 + gn] = acc[i][j][r];
        }
      }
    }
}

// ================= Kernel 2: reduce partials, min-dist + softmax -> V, reach =========
// shfl-based wave reductions: 2 barriers total instead of 24.
__global__ __launch_bounds__(256) void k2_softmax(const float* __restrict__ bhall,
                                                  float* __restrict__ ws) {
  __shared__ float redw[12];
  int b = blockIdx.x, t = threadIdx.x;
  int lane = t & 63, wv = t >> 6;
  float xn = ws[OFF_XN2 + b];
  float lmin = 3.0e38f, lmax = -3.0e38f;
  float Hf4[4] = {0.f, 0.f, 0.f, 0.f};
  if (t < 250) {
    int c0 = t * 4;
    floatx4 S = {0.f, 0.f, 0.f, 0.f}, H = {0.f, 0.f, 0.f, 0.f};
#pragma unroll
    for (int ks = 0; ks < 16; ++ks) {
      floatx4 sv = *(const floatx4*)(ws + OFF_SPART + (size_t)ks * 64000 + b * 1000 + c0);
      floatx4 hv = *(const floatx4*)(ws + OFF_HPART + (size_t)ks * 64000 + b * 1000 + c0);
      S += sv; H += hv;
    }
    floatx4 bh = *(const floatx4*)(bhall + c0);
    floatx4 cn = *(const floatx4*)(ws + OFF_CN2 + c0);
#pragma unroll
    for (int j = 0; j < 4; ++j) {
      float Hf = H[j] + bh[j];
      Hf4[j] = Hf;
      float d2 = xn - 2.f * S[j] + cn[j];
      lmin = fminf(lmin, d2);
      lmax = fmaxf(lmax, Hf);
    }
  }
#pragma unroll
  for (int off = 32; off > 0; off >>= 1) {
    lmin = fminf(lmin, __shfl_down(lmin, off, 64));
    lmax = fmaxf(lmax, __shfl_down(lmax, off, 64));
  }
  if (lane == 0) { redw[wv] = lmin; redw[4 + wv] = lmax; }
  __syncthreads();
  float bmin = fminf(fminf(redw[0], redw[1]), fminf(redw[2], redw[3]));
  float bmax = fmaxf(fmaxf(redw[4], redw[5]), fmaxf(redw[6], redw[7]));
  float lsum = 0.f;
  float e4[4] = {0.f, 0.f, 0.f, 0.f};
  if (t < 250) {
#pragma unroll
    for (int j = 0; j < 4; ++j) {
      e4[j] = expf(Hf4[j] - bmax);
      lsum += e4[j];
    }
  }
#pragma unroll
  for (int off = 32; off > 0; off >>= 1) lsum += __shfl_down(lsum, off, 64);
  if (lane == 0) redw[8 + wv] = lsum;
  __syncthreads();
  float inv = 1.f / (redw[8] + redw[9] + redw[10] + redw[11]);
  if (t < 250)
    *(floatx4*)(ws + OFF_V + b * 1024 + t * 4) =
        (floatx4){e4[0] * inv, e4[1] * inv, e4[2] * inv, e4[3] * inv};
  else  // t in [250,256): pad V[1000..1023] with zeros (4 floats each)
    *(floatx4*)(ws + OFF_V + b * 1024 + 1000 + (t - 250) * 4) =
        (floatx4){0.f, 0.f, 0.f, 0.f};
  if (t == 0) ws[OFF_REACH + b] = 10.f / sqrtf(bmin);
}

// ================= Kernel 3: mem = V@cent (256 blk) + selpre = x@wsel^T (512 blk) ====
__global__ __launch_bounds__(256) void k3_memsel(const float* __restrict__ x,
                                                 const float* __restrict__ cent,
                                                 const float* __restrict__ wsel,
                                                 float* __restrict__ ws) {
  __shared__ __align__(16) ushort u_lds[4 * 64 * TP];
  ushort* Ah = u_lds;
  ushort* Al = u_lds + 64 * TP;
  ushort* Bh = u_lds + 2 * 64 * TP;
  ushort* Bl = u_lds + 3 * 64 * TP;
  int bx = blockIdx.x, t = threadIdx.x;
  int ln15 = t & 15, lq = (t >> 4) & 3, q8 = lq * 8;
  int w = t >> 6, mh = w & 1, nh = w >> 1;

  floatx4 acc[2][2];
#pragma unroll
  for (int i = 0; i < 2; ++i)
#pragma unroll
    for (int j = 0; j < 2; ++j) acc[i][j] = (floatx4){0.f, 0.f, 0.f, 0.f};

  if (bx < 256) {
    // mem = V @ cent : K=1000 (8 splits x 128), N=2048 (32 tiles)
    int tile = bx & 31, ks = bx >> 5;
    int n0 = tile * 64;
    const float* V = ws + OFF_V;
    R2 rA[2], rB[2];
    load_bt(V, 1024, 0, 64, ks * 128,      rA[0], t);
    load_tr(cent, FF, ks * 128,      1000, n0, rB[0], t);
    load_bt(V, 1024, 0, 64, ks * 128 + 32, rA[1], t);
    load_tr(cent, FF, ks * 128 + 32, 1000, n0, rB[1], t);
#pragma unroll
    for (int kc = 0; kc < 4; ++kc) {
      __syncthreads();
      store_bt(rA[kc & 1], Ah, Al, t);
      store_tr(rB[kc & 1], Bh, Bl, t);
      if (kc + 2 < 4) {
        load_bt(V, 1024, 0, 64, ks * 128 + (kc + 2) * 32, rA[kc & 1], t);
        load_tr(cent, FF, ks * 128 + (kc + 2) * 32, 1000, n0, rB[kc & 1], t);
      }
      __syncthreads();
      mfma_tile(Ah, Al, Bh, Bl, ln15, q8, mh, nh, acc);
    }
    float* memp = ws + OFF_MEMP + (size_t)ks * 131072;
#pragma unroll
    for (int i = 0; i < 2; ++i)
#pragma unroll
      for (int j = 0; j < 2; ++j) {
        int gn = n0 + (nh * 2 + j) * 16 + ln15;
#pragma unroll
        for (int r = 0; r < 4; ++r) {
          int gm = (mh * 2 + i) * 16 + lq * 4 + r;
          memp[gm * 2048 + gn] = acc[i][j][r];
        }
      }
  } else {
    // selpre = x @ wsel^T : K=2048 (16 splits x 128), N=2048 (32 tiles)
    int b2 = bx - 256;
    int tile = b2 & 31, ks = b2 >> 5;
    int n0 = tile * 64;
    R2 rA[2], rB[2];
    load_bt(x,    FF, 0,  64,   ks * 128,      rA[0], t);
    load_bt(wsel, FF, n0, 2048, ks * 128,      rB[0], t);
    load_bt(x,    FF, 0,  64,   ks * 128 + 32, rA[1], t);
    load_bt(wsel, FF, n0, 2048, ks * 128 + 32, rB[1], t);
#pragma unroll
    for (int kc = 0; kc < 4; ++kc) {
      __syncthreads();
      store_bt(rA[kc & 1], Ah, Al, t);
      store_bt(rB[kc & 1], Bh, Bl, t);
      if (kc + 2 < 4) {
        load_bt(x,    FF, 0,  64,   ks * 128 + (kc + 2) * 32, rA[kc & 1], t);
        load_bt(wsel, FF, n0, 2048, ks * 128 + (kc + 2) * 32, rB[kc & 1], t);
      }
      __syncthreads();
      mfma_tile(Ah, Al, Bh, Bl, ln15, q8, mh, nh, acc);
    }
    float* selp = ws + OFF_SELP + (size_t)ks * 131072;
#pragma unroll
    for (int i = 0; i < 2; ++i)
#pragma unroll
      for (int j = 0; j < 2; ++j) {
        int gn = n0 + (nh * 2 + j) * 16 + ln15;
#pragma unroll
        for (int r = 0; r < 4; ++r) {
          int gm = (mh * 2 + i) * 16 + lq * 4 + r;
          selp[gm * 2048 + gn] = acc[i][j][r];
        }
      }
  }
}

// ================= Kernel 4: fuse. 64 rows x 8 chunks, one wave each =================
__global__ __launch_bounds__(64) void k4_fuse(const float* __restrict__ x,
                                              const float* __restrict__ bsel,
                                              float* __restrict__ ws, float* __restrict__ out) {
  int bx = blockIdx.x, t = threadIdx.x;
  int row = bx >> 3, ch = bx & 7;
  int f = ch * 256 + t * 4;
  const float* selp = ws + OFF_SELP + (size_t)row * 2048 + f;
  const float* memp = ws + OFF_MEMP + (size_t)row * 2048 + f;
  floatx4 sp = {0.f, 0.f, 0.f, 0.f}, mm = {0.f, 0.f, 0.f, 0.f};
#pragma unroll
  for (int ks = 0; ks < 16; ++ks)
    sp += *(const floatx4*)(selp + (size_t)ks * 131072);
#pragma unroll
  for (int ks = 0; ks < 8; ++ks)
    mm += *(const floatx4*)(memp + (size_t)ks * 131072);
  float4 bs4 = *(const float4*)(bsel + f);
  float4 x4  = *(const float4*)(x + (size_t)row * 2048 + f);
  float rch = ws[OFF_REACH + row];
  float4 inf4;
  floatx4 ft4;
  float nrm2 = 0.f;
#pragma unroll
  for (int j = 0; j < 4; ++j) {
    float sel = tanhf(sp[j] + ((float*)&bs4)[j]);
    float inf = sel * mm[j];
    float ft = rch * (((float*)&x4)[j] + inf);
    ((float*)&inf4)[j] = inf;
    ft4[j] = ft;
    nrm2 += ft * ft;
  }
  *(float4*)(out + 64000 + (size_t)row * 2048 + f) = x4;     // direct_feature
  *(float4*)(out + 195072 + (size_t)row * 2048 + f) = inf4;  // infused_feature
  *(floatx4*)(ws + OFF_FEAT + (size_t)row * 2048 + f) = ft4;
#pragma unroll
  for (int off = 32; off > 0; off >>= 1) nrm2 += __shfl_down(nrm2, off, 64);
  if (t == 0) ws[OFF_NRM2P + row * 8 + ch] = nrm2;
}

// ================= Kernel 5: logp = feat@wcos^T (16 tiles x 16 splits, K=128) ========
__global__ __launch_bounds__(256) void k5_logits(const float* __restrict__ wcos,
                                                 float* __restrict__ ws) {
  __shared__ __align__(16) ushort u_lds[4 * 64 * TP];
  ushort* Ah = u_lds;
  ushort* Al = u_lds + 64 * TP;
  ushort* Bh = u_lds + 2 * 64 * TP;
  ushort* Bl = u_lds + 3 * 64 * TP;
  int bx = blockIdx.x, t = threadIdx.x;
  int tile = bx & 15, ks = bx >> 4;   // ks in [0,16)
  int n0 = tile * 64;
  int ln15 = t & 15, lq = (t >> 4) & 3, q8 = lq * 8;
  int w = t >> 6, mh = w & 1, nh = w >> 1;
  const float* feat = ws + OFF_FEAT;

  floatx4 acc[2][2];
#pragma unroll
  for (int i = 0; i < 2; ++i)
#pragma unroll
    for (int j = 0; j < 2; ++j) acc[i][j] = (floatx4){0.f, 0.f, 0.f, 0.f};

  R2 rA[2], rB[2];
  load_bt(feat, FF, 0,  64,   ks * 128,      rA[0], t);
  load_bt(wcos, FF, n0, 1000, ks * 128,      rB[0], t);
  load_bt(feat, FF, 0,  64,   ks * 128 + 32, rA[1], t);
  load_bt(wcos, FF, n0, 1000, ks * 128 + 32, rB[1], t);
#pragma unroll
  for (int kc = 0; kc < 4; ++kc) {
    __syncthreads();
    store_bt(rA[kc & 1], Ah, Al, t);
    store_bt(rB[kc & 1], Bh, Bl, t);
    if (kc + 2 < 4) {
      load_bt(feat, FF, 0,  64,   ks * 128 + (kc + 2) * 32, rA[kc & 1], t);
      load_bt(wcos, FF, n0, 1000, ks * 128 + (kc + 2) * 32, rB[kc & 1], t);
    }
    __syncthreads();
    mfma_tile(Ah, Al, Bh, Bl, ln15, q8, mh, nh, acc);
  }
  float* logp = ws + OFF_LOGP + (size_t)ks * 64000;
#pragma unroll
  for (int i = 0; i < 2; ++i)
#pragma unroll
    for (int j = 0; j < 2; ++j) {
      int gn = n0 + (nh * 2 + j) * 16 + ln15;
      if (gn < 1000) {
#pragma unroll
        for (int r = 0; r < 4; ++r) {
          int gm = (mh * 2 + i) * 16 + lq * 4 + r;
          logp[gm * 1000 + gn] = acc[i][j][r];
        }
      }
    }
}

// ================= Kernel 6: reduce 16 logit partials, apply cos-norm scales =========
__global__ __launch_bounds__(128) void k6_final(float* __restrict__ ws, float* __restrict__ out) {
  int bx = blockIdx.x, t = threadIdx.x;
  int idx0 = (bx * 128 + t) * 4;
  const float* logp = ws + OFF_LOGP + idx0;
  floatx4 s = {0.f, 0.f, 0.f, 0.f};
#pragma unroll
  for (int ks = 0; ks < 16; ++ks)
    s += *(const floatx4*)(logp + (size_t)ks * 64000);
  floatx4 o4;
  int pb = -1;
  float sfac = 0.f;
#pragma unroll
  for (int j = 0; j < 4; ++j) {
    int idx = idx0 + j;
    int bb = idx / 1000;
    int cc = idx - bb * 1000;
    if (bb != pb) {
      float n2 = 0.f;
#pragma unroll
      for (int q = 0; q < 8; ++q) n2 += ws[OFF_NRM2P + bb * 8 + q];
      sfac = 16.f / (1.f + sqrtf(n2));
      pb = bb;
    }
    o4[j] = s[j] * sfac * ws[OFF_WINV + cc];
  }
  *(floatx4*)(out + idx0) = o4;
}

extern "C" void kernel_launch(void* const* d_in, const int* in_sizes, int n_in,
                              void* d_out, int out_size, void* d_ws, size_t ws_size,
                              hipStream_t stream) {
  const float* x     = (const float*)d_in[0];
  const float* cent  = (const float*)d_in[1];
  const float* whall = (const float*)d_in[2];
  const float* bhall = (const float*)d_in[3];
  const float* wsel  = (const float*)d_in[4];
  const float* bsel  = (const float*)d_in[5];
  const float* wcos  = (const float*)d_in[6];
  float* out = (float*)d_out;
  float* ws  = (float*)d_ws;

  hipLaunchKernelGGL(k1_gemm1,   dim3(512), dim3(256), 0, stream, x, cent, whall, wcos, ws);
  hipLaunchKernelGGL(k2_softmax, dim3(64),  dim3(256), 0, stream, bhall, ws);
  hipLaunchKernelGGL(k3_memsel,  dim3(768), dim3(256), 0, stream, x, cent, wsel, ws);
  hipLaunchKernelGGL(k4_fuse,    dim3(512), dim3(64),  0, stream, x, bsel, ws, out);
  hipLaunchKernelGGL(k5_logits,  dim3(256), dim3(256), 0, stream, wcos, ws);
  hipLaunchKernelGGL(k6_final,   dim3(125), dim3(128), 0, stream, ws, out);
}